// Round 3
// baseline (280.501 us; speedup 1.0000x reference)
//
#include <hip/hip_runtime.h>
#include <hip/hip_bf16.h>

#define N_NODES 4096
#define BATCH   32
#define CIN     32
#define COUT    64
#define DEMB    16
#define NCOL    (BATCH * CIN)      // 1024 columns of the propagation GEMMs
#define KIO     (3 * CIN * COUT)   // 6144 generated-weight elements per node
#define SPLITK  4

typedef __bf16 bf16x8 __attribute__((ext_vector_type(8)));
typedef float  floatx4 __attribute__((ext_vector_type(4)));

__device__ inline void load_lds16(const void* g, void* l) {
    __builtin_amdgcn_global_load_lds(
        (const __attribute__((address_space(1))) void*)g,
        (__attribute__((address_space(3))) void*)l, 16, 0, 0);
}

// ---------------------------------------------------------------------------
// K0: U[n][m] = exp(relu(E[n].E[m])) (UNNORMALIZED, bf16) + invRow[n]=1/rowsum.
// ---------------------------------------------------------------------------
__global__ __launch_bounds__(256) void compute_U_kernel(
        const float* __restrict__ E, __hip_bfloat16* __restrict__ U,
        float* __restrict__ invRow) {
    const int n0   = blockIdx.x * 8;
    const int t    = threadIdx.x;
    const int lane = t & 63, wave = t >> 6;
    __shared__ float red[4][8];

    float en[8][DEMB];
#pragma unroll
    for (int r = 0; r < 8; ++r) {
        const float4* er = (const float4*)&E[(size_t)(n0 + r) * DEMB];
        const float4 a0 = er[0], a1 = er[1], a2 = er[2], a3 = er[3];
        en[r][ 0]=a0.x; en[r][ 1]=a0.y; en[r][ 2]=a0.z; en[r][ 3]=a0.w;
        en[r][ 4]=a1.x; en[r][ 5]=a1.y; en[r][ 6]=a1.z; en[r][ 7]=a1.w;
        en[r][ 8]=a2.x; en[r][ 9]=a2.y; en[r][10]=a2.z; en[r][11]=a2.w;
        en[r][12]=a3.x; en[r][13]=a3.y; en[r][14]=a3.z; en[r][15]=a3.w;
    }

    float sum[8] = {0.f, 0.f, 0.f, 0.f, 0.f, 0.f, 0.f, 0.f};

    for (int tile = 0; tile < 16; ++tile) {
        const int c = tile * 256 + t;
        const float4* em4 = (const float4*)&E[(size_t)c * DEMB];
        const float4 b0 = em4[0], b1 = em4[1], b2 = em4[2], b3 = em4[3];
        float em[DEMB];
        em[ 0]=b0.x; em[ 1]=b0.y; em[ 2]=b0.z; em[ 3]=b0.w;
        em[ 4]=b1.x; em[ 5]=b1.y; em[ 6]=b1.z; em[ 7]=b1.w;
        em[ 8]=b2.x; em[ 9]=b2.y; em[10]=b2.z; em[11]=b2.w;
        em[12]=b3.x; em[13]=b3.y; em[14]=b3.z; em[15]=b3.w;
#pragma unroll
        for (int r = 0; r < 8; ++r) {
            float dt = 0.f;
#pragma unroll
            for (int d = 0; d < DEMB; ++d) dt += en[r][d] * em[d];
            const float ev = __expf(fmaxf(dt, 0.f));
            sum[r] += ev;
            U[(size_t)(n0 + r) * N_NODES + c] = __float2bfloat16(ev);
        }
    }
#pragma unroll
    for (int r = 0; r < 8; ++r)
#pragma unroll
        for (int off = 32; off > 0; off >>= 1) sum[r] += __shfl_xor(sum[r], off);
    if (lane == 0)
#pragma unroll
        for (int r = 0; r < 8; ++r) red[wave][r] = sum[r];
    __syncthreads();
    if (t < 8)
        invRow[n0 + t] = 1.0f / (red[0][t] + red[1][t] + red[2][t] + red[3][t]);
}

// ---------------------------------------------------------------------------
// K1: x[b][m][c] (fp32) -> Xt[m][b*32+c] (bf16) and Bt1[b*32+c][m] (bf16)
// ---------------------------------------------------------------------------
__global__ __launch_bounds__(256) void transpose_kernel(
        const float* __restrict__ x,
        __hip_bfloat16* __restrict__ Xt, __hip_bfloat16* __restrict__ Bt) {
    const int m0 = blockIdx.x * 64;
    const int b  = blockIdx.y;
    const int t  = threadIdx.x;
    __shared__ float tile[64][33];
    {
        const int ml = t >> 2, cg = (t & 3) * 8;
        const float* src = &x[((size_t)b * N_NODES + (m0 + ml)) * CIN + cg];
        const float4 r0 = *(const float4*)src;
        const float4 r1 = *(const float4*)(src + 4);
        tile[ml][cg+0] = r0.x; tile[ml][cg+1] = r0.y; tile[ml][cg+2] = r0.z; tile[ml][cg+3] = r0.w;
        tile[ml][cg+4] = r1.x; tile[ml][cg+5] = r1.y; tile[ml][cg+6] = r1.z; tile[ml][cg+7] = r1.w;
    }
    __syncthreads();
    {
        const int ml = t >> 2, cg = (t & 3) * 8;
        __hip_bfloat16* dst = &Xt[(size_t)(m0 + ml) * NCOL + b * CIN + cg];
#pragma unroll
        for (int j = 0; j < 8; ++j) dst[j] = __float2bfloat16(tile[ml][cg + j]);
    }
    {
        const int c = t >> 3, mg = (t & 7) * 8;
        __hip_bfloat16* dst = &Bt[(size_t)(b * CIN + c) * N_NODES + m0 + mg];
#pragma unroll
        for (int j = 0; j < 8; ++j) dst[j] = __float2bfloat16(tile[mg + j][c]);
    }
}

// ---------------------------------------------------------------------------
// K2 v4: generated weights into the SWIZZLED layout final_kernel reads.
// ---------------------------------------------------------------------------
__global__ __launch_bounds__(256) void gen_w_kernel(
        const float* __restrict__ E, const float* __restrict__ Wp,
        __hip_bfloat16* __restrict__ Wn) {
    const int c   = blockIdx.x >> 3;          // cheb index 0..2
    const int oo0 = (blockIdx.x & 7) * 8;     // output-col group base
    const int nc  = blockIdx.y * 64;          // node group
    const int t   = threadIdx.x;
    const int kk  = t & 31;                   // within-c row index 0..31
    const int oo  = oo0 + (t >> 5);           // output col 0..63

    __shared__ float et[64][DEMB];            // 4 KB: 64 E rows
    ((float4*)et)[t] = ((const float4*)&E[(size_t)nc * DEMB])[t];
    __syncthreads();

    const int srccol = (c * 32 + kk) * 64 + oo;
    float w[DEMB];
#pragma unroll
    for (int d = 0; d < DEMB; ++d) w[d] = Wp[(size_t)d * KIO + srccol];

    const int dstoff = c * 2048 + (oo >> 4) * 512 + (oo & 15) * 32 + kk;
    for (int nl = 0; nl < 64; ++nl) {
        float acc = 0.0f;
#pragma unroll
        for (int d = 0; d < DEMB; ++d) acc += et[nl][d] * w[d];
        Wn[(size_t)(nc + nl) * KIO + dstoff] = __float2bfloat16(acc);
    }
}

// ---------------------------------------------------------------------------
// Shared GEMM geometry: BM=BN=256, BK=64, 512 thr (8 waves 2Mx4N, wave 128x64),
// 2 LDS buffers (128 KB).  Row-pair XOR swizzle, lane-linear global_load_lds
// dest + inverse-swizzled source + swizzled ds_read (rule #21).
// ---------------------------------------------------------------------------
#define GBM 256
#define GBN 256
#define GBK 64

#define GEMM_PREAMBLE                                                          \
    const int t    = threadIdx.x;                                              \
    const int row0 = blockIdx.x * GBM;                                         \
    const int col0 = blockIdx.y * GBN;                                         \
    const int z    = blockIdx.z;                                               \
    const int NT   = (K >> 6) / SPLITK;                                        \
    const int kb0  = z * NT * GBK;                                             \
    const int lane = t & 63, wave = t >> 6;                                    \
    const int l16 = lane & 15, quad = lane >> 4;                               \
    const int wr = wave >> 2, wc = wave & 3;                                   \
    const int R0 = wr * 128 + l16;                                             \
    const int C0 = wc * 64 + l16;                                              \
    const int u_par = (l16 & 1) * 4 + quad;                                    \
    const int Aoff = (R0 >> 1) * 64 + ((u_par ^ ((R0 >> 1) & 7)) * 8);         \
    const int Boff = (C0 >> 1) * 64 + ((u_par ^ ((C0 >> 1) & 7)) * 8);         \
    auto stageA = [&](int buf, int kb, int kh, int s) {                        \
        const int L = s * 512 + t;                                             \
        const int p = L >> 3, j = L & 7;                                       \
        const int u = j ^ (p & 7);                                             \
        const int rr = p * 2 + (u >> 2);                                       \
        const int qq = u & 3;                                                  \
        load_lds16(&A[(size_t)(row0 + rr) * K + kb + kh * 32 + qq * 8],        \
                   &As[buf][(size_t)(kh * 1024 + L) * 8]);                     \
    };                                                                         \
    auto stageB = [&](int buf, int kb, int kh, int s) {                        \
        const int L = s * 512 + t;                                             \
        const int p = L >> 3, j = L & 7;                                       \
        const int u = j ^ (p & 7);                                             \
        const int rr = p * 2 + (u >> 2);                                       \
        const int qq = u & 3;                                                  \
        load_lds16(&Bt[(size_t)(col0 + rr) * K + kb + kh * 32 + qq * 8],       \
                   &Bs[buf][(size_t)(kh * 1024 + L) * 8]);                     \
    };

#define GEMM_EPILOGUE                                                          \
    __hip_bfloat16* Pz = P + (size_t)z * M * NC;                               \
    _Pragma("unroll")                                                          \
    for (int mq = 0; mq < 2; ++mq)                                             \
        _Pragma("unroll")                                                      \
        for (int m = 0; m < 4; ++m)                                            \
            _Pragma("unroll")                                                  \
            for (int n = 0; n < 4; ++n)                                        \
                _Pragma("unroll")                                              \
                for (int r = 0; r < 4; ++r) {                                  \
                    const int rg = row0 + wr * 128 + mq * 64 + m * 16 + quad * 4 + r; \
                    const int cg = col0 + wc * 64 + n * 16 + l16;              \
                    Pz[(size_t)rg * NC + cg] = __float2bfloat16(acc[mq * 4 + m][n][r]); \
                }

// ---------------------------------------------------------------------------
// K3-A: de-pinned deep pipeline (raw barriers + setprio + counted vmcnt ONLY;
// no sched_barrier / no lgkmcnt asm — compiler fences its own ds_reads).
// ---------------------------------------------------------------------------
__global__ __launch_bounds__(512, 2) void gemm_pipe_kernel(
        const __hip_bfloat16* __restrict__ A,    // [M][K]
        const __hip_bfloat16* __restrict__ Bt,   // [NC][K]
        __hip_bfloat16* __restrict__ P,          // [SPLITK][M][NC]
        int M, int NC, int K) {
    __shared__ alignas(16) __hip_bfloat16 As[2][16384];
    __shared__ alignas(16) __hip_bfloat16 Bs[2][16384];
    GEMM_PREAMBLE

    floatx4 acc[8][4] = {};

    // prologue: tile0 fully + tile1 kh0; wait tile0 (4 of t1 in flight)
#pragma unroll
    for (int s = 0; s < 2; ++s) stageA(0, kb0, 0, s);
#pragma unroll
    for (int s = 0; s < 2; ++s) stageB(0, kb0, 0, s);
#pragma unroll
    for (int s = 0; s < 2; ++s) stageA(0, kb0, 1, s);
#pragma unroll
    for (int s = 0; s < 2; ++s) stageB(0, kb0, 1, s);
#pragma unroll
    for (int s = 0; s < 2; ++s) stageA(1, kb0 + GBK, 0, s);
#pragma unroll
    for (int s = 0; s < 2; ++s) stageB(1, kb0 + GBK, 0, s);
    asm volatile("s_waitcnt vmcnt(4)" ::: "memory");
    __builtin_amdgcn_s_barrier();

    for (int tt = 0; tt < NT; ++tt) {
        const int buf = tt & 1;
        const int nb1 = (tt + 1) & 1;
        const int nb2 = buf;
        const int kb1 = kb0 + (tt + 1) * GBK;
        const int kb2 = kb0 + (tt + 2) * GBK;
        const bool g1 = (tt + 1 < NT), g2 = (tt + 2 < NT);

        bf16x8 bfrag[4], afrag[4];

        // ===== phase 1: kq=0, mq=0 =====
#pragma unroll
        for (int n = 0; n < 4; ++n)
            bfrag[n] = *(const bf16x8*)&Bs[buf][n * 512 + Boff];
#pragma unroll
        for (int m = 0; m < 4; ++m)
            afrag[m] = *(const bf16x8*)&As[buf][m * 512 + Aoff];
        if (g1) { stageA(nb1, kb1, 1, 0); stageA(nb1, kb1, 1, 1); }
        __builtin_amdgcn_s_barrier();
        __builtin_amdgcn_s_setprio(1);
#pragma unroll
        for (int m = 0; m < 4; ++m)
#pragma unroll
            for (int n = 0; n < 4; ++n)
                acc[m][n] = __builtin_amdgcn_mfma_f32_16x16x32_bf16(
                                afrag[m], bfrag[n], acc[m][n], 0, 0, 0);
        __builtin_amdgcn_s_setprio(0);
        __builtin_amdgcn_s_barrier();

        // ===== phase 2: kq=0, mq=1 =====
#pragma unroll
        for (int m = 0; m < 4; ++m)
            afrag[m] = *(const bf16x8*)&As[buf][2048 + m * 512 + Aoff];
        if (g1) { stageB(nb1, kb1, 1, 0); stageB(nb1, kb1, 1, 1); }
        __builtin_amdgcn_s_barrier();
        __builtin_amdgcn_s_setprio(1);
#pragma unroll
        for (int m = 0; m < 4; ++m)
#pragma unroll
            for (int n = 0; n < 4; ++n)
                acc[4 + m][n] = __builtin_amdgcn_mfma_f32_16x16x32_bf16(
                                    afrag[m], bfrag[n], acc[4 + m][n], 0, 0, 0);
        __builtin_amdgcn_s_setprio(0);
        __builtin_amdgcn_s_barrier();

        // ===== phase 3: kq=1, mq=0 =====
#pragma unroll
        for (int n = 0; n < 4; ++n)
            bfrag[n] = *(const bf16x8*)&Bs[buf][8192 + n * 512 + Boff];
#pragma unroll
        for (int m = 0; m < 4; ++m)
            afrag[m] = *(const bf16x8*)&As[buf][8192 + m * 512 + Aoff];
        if (g2) { stageA(nb2, kb2, 0, 0); stageA(nb2, kb2, 0, 1); }
        __builtin_amdgcn_s_barrier();
        __builtin_amdgcn_s_setprio(1);
#pragma unroll
        for (int m = 0; m < 4; ++m)
#pragma unroll
            for (int n = 0; n < 4; ++n)
                acc[m][n] = __builtin_amdgcn_mfma_f32_16x16x32_bf16(
                                afrag[m], bfrag[n], acc[m][n], 0, 0, 0);
        __builtin_amdgcn_s_setprio(0);
        __builtin_amdgcn_s_barrier();

        // ===== phase 4: kq=1, mq=1 =====
#pragma unroll
        for (int m = 0; m < 4; ++m)
            afrag[m] = *(const bf16x8*)&As[buf][8192 + 2048 + m * 512 + Aoff];
        if (g2) { stageB(nb2, kb2, 0, 0); stageB(nb2, kb2, 0, 1); }
        __builtin_amdgcn_s_barrier();
        __builtin_amdgcn_s_setprio(1);
#pragma unroll
        for (int m = 0; m < 4; ++m)
#pragma unroll
            for (int n = 0; n < 4; ++n)
                acc[4 + m][n] = __builtin_amdgcn_mfma_f32_16x16x32_bf16(
                                    afrag[m], bfrag[n], acc[4 + m][n], 0, 0, 0);
        __builtin_amdgcn_s_setprio(0);
        if (tt < NT - 2) asm volatile("s_waitcnt vmcnt(4)" ::: "memory");
        else             asm volatile("s_waitcnt vmcnt(0)" ::: "memory");
        __builtin_amdgcn_s_barrier();
    }

    GEMM_EPILOGUE
}

// ---------------------------------------------------------------------------
// K3-B: same geometry, classic compiler-scheduled double-buffer (m97 style):
// one __syncthreads per K-tile, stage t+1 then compute t, compiler fences.
// ---------------------------------------------------------------------------
__global__ __launch_bounds__(512, 2) void gemm_classic_kernel(
        const __hip_bfloat16* __restrict__ A,    // [M][K]
        const __hip_bfloat16* __restrict__ Bt,   // [NC][K]
        __hip_bfloat16* __restrict__ P,          // [SPLITK][M][NC]
        int M, int NC, int K) {
    __shared__ alignas(16) __hip_bfloat16 As[2][16384];
    __shared__ alignas(16) __hip_bfloat16 Bs[2][16384];
    GEMM_PREAMBLE

    floatx4 acc[8][4] = {};

    // prologue: stage tile0 into buf0
#pragma unroll
    for (int kh = 0; kh < 2; ++kh)
#pragma unroll
        for (int s = 0; s < 2; ++s) { stageA(0, kb0, kh, s); stageB(0, kb0, kh, s); }

    for (int tt = 0; tt < NT; ++tt) {
        const int buf = tt & 1;
        __syncthreads();   // compiler drains vmcnt/lgkmcnt: tile tt staged & prior reads done
        if (tt + 1 < NT) {
            const int kb1 = kb0 + (tt + 1) * GBK;
#pragma unroll
            for (int kh = 0; kh < 2; ++kh)
#pragma unroll
                for (int s = 0; s < 2; ++s) { stageA(buf ^ 1, kb1, kh, s); stageB(buf ^ 1, kb1, kh, s); }
        }
        bf16x8 bfrag[4], afrag[4];
#pragma unroll
        for (int kq = 0; kq < 2; ++kq) {
            const int kofs = kq * 8192;
#pragma unroll
            for (int n = 0; n < 4; ++n)
                bfrag[n] = *(const bf16x8*)&Bs[buf][kofs + n * 512 + Boff];
#pragma unroll
            for (int mq = 0; mq < 2; ++mq) {
#pragma unroll
                for (int m = 0; m < 4; ++m)
                    afrag[m] = *(const bf16x8*)&As[buf][kofs + mq * 2048 + m * 512 + Aoff];
#pragma unroll
                for (int m = 0; m < 4; ++m)
#pragma unroll
                    for (int n = 0; n < 4; ++n)
                        acc[mq * 4 + m][n] = __builtin_amdgcn_mfma_f32_16x16x32_bf16(
                                                 afrag[m], bfrag[n], acc[mq * 4 + m][n], 0, 0, 0);
            }
        }
    }

    GEMM_EPILOGUE
}

// ---------------------------------------------------------------------------
// K3b: combine1 -> Y1 = bf16(inv[row] * sum_z Pz), plus transposed Y1t
// ---------------------------------------------------------------------------
__global__ __launch_bounds__(256) void combine1_kernel(
        const __hip_bfloat16* __restrict__ P, const float* __restrict__ invRow,
        __hip_bfloat16* __restrict__ Y, __hip_bfloat16* __restrict__ Yt,
        int M, int NC) {
    const int c0 = blockIdx.x * 64, m0 = blockIdx.y * 64;
    const int t = threadIdx.x;
    __shared__ float tile[64][65];
    const size_t stride = (size_t)M * NC;
#pragma unroll
    for (int j = 0; j < 16; ++j) {
        const int lin = t + j * 256;
        const int r = lin >> 6, c = lin & 63;
        const size_t idx = (size_t)(m0 + r) * NC + c0 + c;
        float s = 0.f;
#pragma unroll
        for (int z = 0; z < SPLITK; ++z) s += __bfloat162float(P[idx + z * stride]);
        s *= invRow[m0 + r];
        tile[r][c] = s;
        Y[idx] = __float2bfloat16(s);
    }
    __syncthreads();
#pragma unroll
    for (int j = 0; j < 16; ++j) {
        const int lin = t + j * 256;
        const int c = lin >> 6, r = lin & 63;
        Yt[(size_t)(c0 + c) * M + m0 + r] = __float2bfloat16(tile[r][c]);
    }
}

// ---------------------------------------------------------------------------
// K3c: combine2 -> Y2 = bf16(2*inv[row]*sum_z Pz - Xt)  (Chebyshev T2)
// ---------------------------------------------------------------------------
__global__ __launch_bounds__(256) void combine2_kernel(
        const __hip_bfloat16* __restrict__ P, const float* __restrict__ invRow,
        const __hip_bfloat16* __restrict__ sub, __hip_bfloat16* __restrict__ Y2,
        int M, int NC) {
    const size_t stride = (size_t)M * NC;
    const size_t idx0 = (size_t)blockIdx.x * 4096 + threadIdx.x;
#pragma unroll
    for (int j = 0; j < 16; ++j) {
        const size_t idx = idx0 + (size_t)j * 256;
        float s = 0.f;
#pragma unroll
        for (int z = 0; z < SPLITK; ++z) s += __bfloat162float(P[idx + z * stride]);
        s *= invRow[idx >> 10];          // row = idx / NCOL (NCOL = 1024)
        Y2[idx] = __float2bfloat16(2.0f * s - __bfloat162float(sub[idx]));
    }
}

// ---------------------------------------------------------------------------
// K4: per-node grouped GEMM via MFMA.
// ---------------------------------------------------------------------------
__global__ __launch_bounds__(256) void final_kernel(
        const __hip_bfloat16* __restrict__ Xt, const __hip_bfloat16* __restrict__ Y1,
        const __hip_bfloat16* __restrict__ Y2, const __hip_bfloat16* __restrict__ Wn,
        const float* __restrict__ E, const float* __restrict__ bias_pool,
        float* __restrict__ out) {
    const int t    = threadIdx.x;
    const int lane = t & 63, wave = t >> 6;
    const int l16  = lane & 15, quad = lane >> 4;
    const int n    = blockIdx.x * 4 + wave;

    const __hip_bfloat16* srcs[3] = {Xt, Y1, Y2};
    const __hip_bfloat16* Wnode = Wn + (size_t)n * KIO;   // [c][ot][l16][kk]

    floatx4 acc[2][4] = {};   // [mt][ot]

#pragma unroll
    for (int c = 0; c < 3; ++c) {
        bf16x8 af[2];
#pragma unroll
        for (int mt = 0; mt < 2; ++mt)
            af[mt] = *(const bf16x8*)&srcs[c][(size_t)n * NCOL +
                                              (mt * 16 + l16) * 32 + quad * 8];
#pragma unroll
        for (int ot = 0; ot < 4; ++ot) {
            const bf16x8 bfr = *(const bf16x8*)&Wnode[(size_t)c * 2048 +
                                                      ot * 512 + l16 * 32 + quad * 8];
#pragma unroll
            for (int mt = 0; mt < 2; ++mt)
                acc[mt][ot] = __builtin_amdgcn_mfma_f32_16x16x32_bf16(
                                  af[mt], bfr, acc[mt][ot], 0, 0, 0);
        }
    }

    float en[DEMB];
#pragma unroll
    for (int d = 0; d < DEMB; ++d) en[d] = E[(size_t)n * DEMB + d];
#pragma unroll
    for (int ot = 0; ot < 4; ++ot) {
        float bv = 0.f;
        const int o = ot * 16 + l16;
#pragma unroll
        for (int d = 0; d < DEMB; ++d) bv += en[d] * bias_pool[d * COUT + o];
#pragma unroll
        for (int mt = 0; mt < 2; ++mt)
#pragma unroll
            for (int r = 0; r < 4; ++r) {
                const int b = mt * 16 + quad * 4 + r;
                out[((size_t)b * N_NODES + n) * COUT + o] = acc[mt][ot][r] + bv;
            }
    }
}

// ---------------------------------------------------------------------------
extern "C" void kernel_launch(void* const* d_in, const int* in_sizes, int n_in,
                              void* d_out, int out_size, void* d_ws, size_t ws_size,
                              hipStream_t stream) {
    (void)in_sizes; (void)n_in; (void)out_size; (void)ws_size;
    const float* x  = (const float*)d_in[0];
    const float* E  = (const float*)d_in[1];
    // d_in[2] = laplacian_mx, unused by the reference forward
    const float* Wp = (const float*)d_in[3];
    const float* bp = (const float*)d_in[4];
    float* out = (float*)d_out;

    char* ws = (char*)d_ws;
    __hip_bfloat16* U   = (__hip_bfloat16*)(ws);                 // 33554432 B (unnormalized exp)
    __hip_bfloat16* Xt  = (__hip_bfloat16*)(ws + 33554432);      //  8388608 B
    __hip_bfloat16* Bt1 = (__hip_bfloat16*)(ws + 41943040);      //  8388608 B (X^T; reused as Y2)
    __hip_bfloat16* Y1  = (__hip_bfloat16*)(ws + 50331648);      //  8388608 B
    __hip_bfloat16* Y1t = (__hip_bfloat16*)(ws + 58720256);      //  8388608 B
    __hip_bfloat16* P   = (__hip_bfloat16*)(ws + 67108864);      // 33554432 B bf16 partials [4][4096][1024]
    float*       invRow = (float*)(ws + 100663296);              //    16384 B (dead before Wn written)
    __hip_bfloat16* Wn  = (__hip_bfloat16*)(ws + 67108864);      // 50331648 B (SAME region: P+invRow dead before gen_w)
    // total ws use: 117440512 B

    compute_U_kernel<<<N_NODES / 8, 256, 0, stream>>>(E, U, invRow);
    transpose_kernel<<<dim3(N_NODES / 64, BATCH), 256, 0, stream>>>(x, Xt, Bt1);
    // Y1 = inv * (U @ X)  — variant A: de-pinned deep pipeline
    gemm_pipe_kernel<<<dim3(N_NODES / GBM, NCOL / GBN, SPLITK), 512, 0, stream>>>(
        U, Bt1, P, N_NODES, NCOL, N_NODES);
    combine1_kernel<<<dim3(NCOL / 64, N_NODES / 64), 256, 0, stream>>>(
        P, invRow, Y1, Y1t, N_NODES, NCOL);
    // Y2 = 2*inv*(U @ Y1) - X  — variant B: classic compiler-scheduled dbuf
    gemm_classic_kernel<<<dim3(N_NODES / GBM, NCOL / GBN, SPLITK), 512, 0, stream>>>(
        U, Y1t, P, N_NODES, NCOL, N_NODES);
    combine2_kernel<<<dim3(N_NODES * NCOL / 4096), 256, 0, stream>>>(
        P, invRow, Xt, Bt1, N_NODES, NCOL);
    // gen_w AFTER combine2: Wn shares the P/invRow region
    gen_w_kernel<<<dim3(24, N_NODES / 64), 256, 0, stream>>>(E, Wp, Wn);
    final_kernel<<<N_NODES / 4, 256, 0, stream>>>(Xt, Y1, Bt1, Wn, E, bp, out);
}

// Round 4
// 279.433 us; speedup vs baseline: 1.0038x; 1.0038x over previous
//
#include <hip/hip_runtime.h>
#include <hip/hip_bf16.h>

#define N_NODES 4096
#define BATCH   32
#define CIN     32
#define COUT    64
#define DEMB    16
#define NCOL    (BATCH * CIN)      // 1024 columns of the propagation GEMMs
#define KIO     (3 * CIN * COUT)   // 6144 generated-weight elements per node
#define SPLITK  2

typedef __bf16 bf16x8 __attribute__((ext_vector_type(8)));
typedef float  floatx4 __attribute__((ext_vector_type(4)));

__device__ inline void load_lds16(const void* g, void* l) {
    __builtin_amdgcn_global_load_lds(
        (const __attribute__((address_space(1))) void*)g,
        (__attribute__((address_space(3))) void*)l, 16, 0, 0);
}

// ---------------------------------------------------------------------------
// K0: U[n][m] = exp(relu(E[n].E[m])) (UNNORMALIZED, bf16) + invRow[n]=1/rowsum.
// ---------------------------------------------------------------------------
__global__ __launch_bounds__(256) void compute_U_kernel(
        const float* __restrict__ E, __hip_bfloat16* __restrict__ U,
        float* __restrict__ invRow) {
    const int n0   = blockIdx.x * 8;
    const int t    = threadIdx.x;
    const int lane = t & 63, wave = t >> 6;
    __shared__ float red[4][8];

    float en[8][DEMB];
#pragma unroll
    for (int r = 0; r < 8; ++r) {
        const float4* er = (const float4*)&E[(size_t)(n0 + r) * DEMB];
        const float4 a0 = er[0], a1 = er[1], a2 = er[2], a3 = er[3];
        en[r][ 0]=a0.x; en[r][ 1]=a0.y; en[r][ 2]=a0.z; en[r][ 3]=a0.w;
        en[r][ 4]=a1.x; en[r][ 5]=a1.y; en[r][ 6]=a1.z; en[r][ 7]=a1.w;
        en[r][ 8]=a2.x; en[r][ 9]=a2.y; en[r][10]=a2.z; en[r][11]=a2.w;
        en[r][12]=a3.x; en[r][13]=a3.y; en[r][14]=a3.z; en[r][15]=a3.w;
    }

    float sum[8] = {0.f, 0.f, 0.f, 0.f, 0.f, 0.f, 0.f, 0.f};

    for (int tile = 0; tile < 16; ++tile) {
        const int c = tile * 256 + t;
        const float4* em4 = (const float4*)&E[(size_t)c * DEMB];
        const float4 b0 = em4[0], b1 = em4[1], b2 = em4[2], b3 = em4[3];
        float em[DEMB];
        em[ 0]=b0.x; em[ 1]=b0.y; em[ 2]=b0.z; em[ 3]=b0.w;
        em[ 4]=b1.x; em[ 5]=b1.y; em[ 6]=b1.z; em[ 7]=b1.w;
        em[ 8]=b2.x; em[ 9]=b2.y; em[10]=b2.z; em[11]=b2.w;
        em[12]=b3.x; em[13]=b3.y; em[14]=b3.z; em[15]=b3.w;
#pragma unroll
        for (int r = 0; r < 8; ++r) {
            float dt = 0.f;
#pragma unroll
            for (int d = 0; d < DEMB; ++d) dt += en[r][d] * em[d];
            const float ev = __expf(fmaxf(dt, 0.f));
            sum[r] += ev;
            U[(size_t)(n0 + r) * N_NODES + c] = __float2bfloat16(ev);
        }
    }
#pragma unroll
    for (int r = 0; r < 8; ++r)
#pragma unroll
        for (int off = 32; off > 0; off >>= 1) sum[r] += __shfl_xor(sum[r], off);
    if (lane == 0)
#pragma unroll
        for (int r = 0; r < 8; ++r) red[wave][r] = sum[r];
    __syncthreads();
    if (t < 8)
        invRow[n0 + t] = 1.0f / (red[0][t] + red[1][t] + red[2][t] + red[3][t]);
}

// ---------------------------------------------------------------------------
// K1: x[b][m][c] (fp32) -> Xt[m][b*32+c] (bf16) and Bt1[b*32+c][m] (bf16)
// ---------------------------------------------------------------------------
__global__ __launch_bounds__(256) void transpose_kernel(
        const float* __restrict__ x,
        __hip_bfloat16* __restrict__ Xt, __hip_bfloat16* __restrict__ Bt) {
    const int m0 = blockIdx.x * 64;
    const int b  = blockIdx.y;
    const int t  = threadIdx.x;
    __shared__ float tile[64][33];
    {
        const int ml = t >> 2, cg = (t & 3) * 8;
        const float* src = &x[((size_t)b * N_NODES + (m0 + ml)) * CIN + cg];
        const float4 r0 = *(const float4*)src;
        const float4 r1 = *(const float4*)(src + 4);
        tile[ml][cg+0] = r0.x; tile[ml][cg+1] = r0.y; tile[ml][cg+2] = r0.z; tile[ml][cg+3] = r0.w;
        tile[ml][cg+4] = r1.x; tile[ml][cg+5] = r1.y; tile[ml][cg+6] = r1.z; tile[ml][cg+7] = r1.w;
    }
    __syncthreads();
    {
        const int ml = t >> 2, cg = (t & 3) * 8;
        __hip_bfloat16* dst = &Xt[(size_t)(m0 + ml) * NCOL + b * CIN + cg];
#pragma unroll
        for (int j = 0; j < 8; ++j) dst[j] = __float2bfloat16(tile[ml][cg + j]);
    }
    {
        const int c = t >> 3, mg = (t & 7) * 8;
        __hip_bfloat16* dst = &Bt[(size_t)(b * CIN + c) * N_NODES + m0 + mg];
#pragma unroll
        for (int j = 0; j < 8; ++j) dst[j] = __float2bfloat16(tile[mg + j][c]);
    }
}

// ---------------------------------------------------------------------------
// K2 v4: generated weights into the SWIZZLED layout final_kernel reads.
// ---------------------------------------------------------------------------
__global__ __launch_bounds__(256) void gen_w_kernel(
        const float* __restrict__ E, const float* __restrict__ Wp,
        __hip_bfloat16* __restrict__ Wn) {
    const int c   = blockIdx.x >> 3;          // cheb index 0..2
    const int oo0 = (blockIdx.x & 7) * 8;     // output-col group base
    const int nc  = blockIdx.y * 64;          // node group
    const int t   = threadIdx.x;
    const int kk  = t & 31;                   // within-c row index 0..31
    const int oo  = oo0 + (t >> 5);           // output col 0..63

    __shared__ float et[64][DEMB];            // 4 KB: 64 E rows
    ((float4*)et)[t] = ((const float4*)&E[(size_t)nc * DEMB])[t];
    __syncthreads();

    const int srccol = (c * 32 + kk) * 64 + oo;
    float w[DEMB];
#pragma unroll
    for (int d = 0; d < DEMB; ++d) w[d] = Wp[(size_t)d * KIO + srccol];

    const int dstoff = c * 2048 + (oo >> 4) * 512 + (oo & 15) * 32 + kk;
    for (int nl = 0; nl < 64; ++nl) {
        float acc = 0.0f;
#pragma unroll
        for (int d = 0; d < DEMB; ++d) acc += et[nl][d] * w[d];
        Wn[(size_t)(nc + nl) * KIO + dstoff] = __float2bfloat16(acc);
    }
}

// ---------------------------------------------------------------------------
// K3 v5: de-pinned deep-pipeline split-K GEMM (A/B winner structure).
//   BM=128, BN=256, BK=64, 512 thr = 8 waves (2 Mx4 N), wave tile 64x64.
//   SPLITK=2 -> grid 32x4x2 = 256 blocks = 1/CU, NT=32 K-tiles (long main
//   loop: fill+drain amortized 2x vs round-2's NT=16).
//   LDS 96 KB: As[2][128x64], Bs[2][256x64]; per tile 2 K-half chunks
//   (kh = 32 cols); row-pair XOR granule swizzle (same verified bijection
//   as rounds 1-3), lane-linear global_load_lds dest + inverse-swizzled
//   global source + swizzled ds_read (rule #21).
//   2 phases per K-tile (kq=0,1): 8 ds_read_b128 -> issue 3 stage calls ->
//   barrier -> setprio(1)+16 MFMA+setprio(0) -> barrier.
//   Stage slots: ph1 = {A,B,B}.kh1 of tile t+1; ph2 = {A,B,B}.kh0 of t+2.
//   vmcnt ledger: 9 outstanding max; boundary wait vmcnt(3) validates tile
//   t+1 fully (its 6 loads older than t+2.kh0's 3); vmcnt(0) only at NT-2.
//   No sched_barrier / no lgkmcnt asm (round-3 A/B: pins cost ~10%).
// ---------------------------------------------------------------------------
#define GBM 128
#define GBN 256
#define GBK 64

__global__ __launch_bounds__(512, 2) void gemm_splitk_kernel(
        const __hip_bfloat16* __restrict__ A,    // [M][K]
        const __hip_bfloat16* __restrict__ Bt,   // [NC][K]
        __hip_bfloat16* __restrict__ P,          // [SPLITK][M][NC] bf16 partials
        int M, int NC, int K) {
    const int t    = threadIdx.x;
    const int row0 = blockIdx.x * GBM;
    const int col0 = blockIdx.y * GBN;
    const int z    = blockIdx.z;
    const int NT   = (K >> 6) / SPLITK;        // 32 K-tiles of BK=64 per block
    const int kb0  = z * NT * GBK;

    __shared__ alignas(16) __hip_bfloat16 As[2][8192];   // 2 x 16 KB (2 kh x 4096)
    __shared__ alignas(16) __hip_bfloat16 Bs[2][16384];  // 2 x 32 KB (2 kh x 8192)

    const int lane = t & 63, wave = t >> 6;
    const int l16 = lane & 15, quad = lane >> 4;
    const int wr = wave >> 2, wc = wave & 3;   // 2 x 4 wave grid, wave 64x64

    // per-thread ds_read bases (elements within a kh chunk)
    const int R0 = wr * 64 + l16;              // A row base
    const int C0 = wc * 64 + l16;              // B row base
    const int u_par = (l16 & 1) * 4 + quad;
    const int Abase = (R0 >> 1) * 64 + ((u_par ^ ((R0 >> 1) & 7)) * 8);
    const int Bbase = (C0 >> 1) * 64 + ((u_par ^ ((C0 >> 1) & 7)) * 8);

    // stage: A half-chunk = 512 granules (1 call); B half-chunk = 1024 (2 calls)
    auto stageA = [&](int buf, int kb, int kh) {
        const int L = t;
        const int p = L >> 3, j = L & 7;
        const int u = j ^ (p & 7);
        const int rr = p * 2 + (u >> 2);
        const int qq = u & 3;
        load_lds16(&A[(size_t)(row0 + rr) * K + kb + kh * 32 + qq * 8],
                   &As[buf][(size_t)(kh * 4096 + L * 8)]);
    };
    auto stageB = [&](int buf, int kb, int kh, int s) {
        const int L = s * 512 + t;
        const int p = L >> 3, j = L & 7;
        const int u = j ^ (p & 7);
        const int rr = p * 2 + (u >> 2);
        const int qq = u & 3;
        load_lds16(&Bt[(size_t)(col0 + rr) * K + kb + kh * 32 + qq * 8],
                   &Bs[buf][(size_t)(kh * 8192 + L * 8)]);
    };

    floatx4 acc[4][4] = {};

    // ---- prologue: tile0 full (6 loads) + tile1.kh0 (3); wait tile0.
    stageA(0, kb0, 0); stageB(0, kb0, 0, 0); stageB(0, kb0, 0, 1);
    stageA(0, kb0, 1); stageB(0, kb0, 1, 0); stageB(0, kb0, 1, 1);
    stageA(1, kb0 + GBK, 0); stageB(1, kb0 + GBK, 0, 0); stageB(1, kb0 + GBK, 0, 1);
    asm volatile("s_waitcnt vmcnt(3)" ::: "memory");
    __builtin_amdgcn_s_barrier();

    for (int tt = 0; tt < NT; ++tt) {
        const int buf = tt & 1;
        const int nb1 = buf ^ 1;               // buffer of tile t+1
        const int nb2 = buf;                   // buffer of tile t+2
        const int kb1 = kb0 + (tt + 1) * GBK;
        const int kb2 = kb0 + (tt + 2) * GBK;
        const bool g1 = (tt + 1 < NT), g2 = (tt + 2 < NT);

        bf16x8 afrag[4], bfrag[4];

        // ===== phase 1: kq=0 (kh0) =====
#pragma unroll
        for (int m = 0; m < 4; ++m)
            afrag[m] = *(const bf16x8*)&As[buf][m * 512 + Abase];
#pragma unroll
        for (int n = 0; n < 4; ++n)
            bfrag[n] = *(const bf16x8*)&Bs[buf][n * 512 + Bbase];
        if (g1) { stageA(nb1, kb1, 1); stageB(nb1, kb1, 1, 0); stageB(nb1, kb1, 1, 1); }
        __builtin_amdgcn_s_barrier();
        __builtin_amdgcn_s_setprio(1);
#pragma unroll
        for (int m = 0; m < 4; ++m)
#pragma unroll
            for (int n = 0; n < 4; ++n)
                acc[m][n] = __builtin_amdgcn_mfma_f32_16x16x32_bf16(
                                afrag[m], bfrag[n], acc[m][n], 0, 0, 0);
        __builtin_amdgcn_s_setprio(0);
        __builtin_amdgcn_s_barrier();

        // ===== phase 2: kq=1 (kh1) =====
#pragma unroll
        for (int m = 0; m < 4; ++m)
            afrag[m] = *(const bf16x8*)&As[buf][4096 + m * 512 + Abase];
#pragma unroll
        for (int n = 0; n < 4; ++n)
            bfrag[n] = *(const bf16x8*)&Bs[buf][8192 + n * 512 + Bbase];
        if (g2) { stageA(nb2, kb2, 0); stageB(nb2, kb2, 0, 0); stageB(nb2, kb2, 0, 1); }
        __builtin_amdgcn_s_barrier();
        __builtin_amdgcn_s_setprio(1);
#pragma unroll
        for (int m = 0; m < 4; ++m)
#pragma unroll
            for (int n = 0; n < 4; ++n)
                acc[m][n] = __builtin_amdgcn_mfma_f32_16x16x32_bf16(
                                afrag[m], bfrag[n], acc[m][n], 0, 0, 0);
        __builtin_amdgcn_s_setprio(0);
        // boundary: counted wait validates tile t+1; drain only at the tail
        if (tt < NT - 2) asm volatile("s_waitcnt vmcnt(3)" ::: "memory");
        else             asm volatile("s_waitcnt vmcnt(0)" ::: "memory");
        __builtin_amdgcn_s_barrier();
    }

    __hip_bfloat16* Pz = P + (size_t)z * M * NC;
#pragma unroll
    for (int m = 0; m < 4; ++m)
#pragma unroll
        for (int n = 0; n < 4; ++n)
#pragma unroll
            for (int r = 0; r < 4; ++r) {
                const int rg = row0 + wr * 64 + m * 16 + quad * 4 + r;
                const int cg = col0 + wc * 64 + n * 16 + l16;
                Pz[(size_t)rg * NC + cg] = __float2bfloat16(acc[m][n][r]);
            }
}

// ---------------------------------------------------------------------------
// K3b: combine1 -> Y1 = bf16(inv[row] * sum_z Pz), plus transposed Y1t
// ---------------------------------------------------------------------------
__global__ __launch_bounds__(256) void combine1_kernel(
        const __hip_bfloat16* __restrict__ P, const float* __restrict__ invRow,
        __hip_bfloat16* __restrict__ Y, __hip_bfloat16* __restrict__ Yt,
        int M, int NC) {
    const int c0 = blockIdx.x * 64, m0 = blockIdx.y * 64;
    const int t = threadIdx.x;
    __shared__ float tile[64][65];
    const size_t stride = (size_t)M * NC;
#pragma unroll
    for (int j = 0; j < 16; ++j) {
        const int lin = t + j * 256;
        const int r = lin >> 6, c = lin & 63;
        const size_t idx = (size_t)(m0 + r) * NC + c0 + c;
        float s = 0.f;
#pragma unroll
        for (int z = 0; z < SPLITK; ++z) s += __bfloat162float(P[idx + z * stride]);
        s *= invRow[m0 + r];
        tile[r][c] = s;
        Y[idx] = __float2bfloat16(s);
    }
    __syncthreads();
#pragma unroll
    for (int j = 0; j < 16; ++j) {
        const int lin = t + j * 256;
        const int c = lin >> 6, r = lin & 63;
        Yt[(size_t)(c0 + c) * M + m0 + r] = __float2bfloat16(tile[r][c]);
    }
}

// ---------------------------------------------------------------------------
// K4 v2: per-node grouped GEMM via MFMA, with combine2 FUSED:
//   Y2 operand (c=2) computed in registers as 2*inv[n]*(P0+P1) - Xt.
//   P/Xt/Y1 share the [node][b*32+c] frag layout, so the Xt frags loaded for
//   the c=0 term are reused for the Chebyshev subtraction.
// ---------------------------------------------------------------------------
__global__ __launch_bounds__(256) void final_kernel(
        const __hip_bfloat16* __restrict__ Xt, const __hip_bfloat16* __restrict__ Y1,
        const __hip_bfloat16* __restrict__ P,  const float* __restrict__ invRow,
        const __hip_bfloat16* __restrict__ Wn,
        const float* __restrict__ E, const float* __restrict__ bias_pool,
        float* __restrict__ out) {
    const int t    = threadIdx.x;
    const int lane = t & 63, wave = t >> 6;
    const int l16  = lane & 15, quad = lane >> 4;
    const int n    = blockIdx.x * 4 + wave;

    const __hip_bfloat16* Wnode = Wn + (size_t)n * KIO;   // [c][ot][l16][kk]
    const float inv = invRow[n];
    const size_t pstride = (size_t)N_NODES * NCOL;

    floatx4 acc[2][4] = {};   // [mt][ot]

    bf16x8 afX[2], afY1[2], afY2[2];
#pragma unroll
    for (int mt = 0; mt < 2; ++mt) {
        const size_t fo = (size_t)n * NCOL + (mt * 16 + l16) * 32 + quad * 8;
        afX[mt]  = *(const bf16x8*)&Xt[fo];
        afY1[mt] = *(const bf16x8*)&Y1[fo];
        const bf16x8 p0 = *(const bf16x8*)&P[fo];
        const bf16x8 p1 = *(const bf16x8*)&P[fo + pstride];
#pragma unroll
        for (int j = 0; j < 8; ++j) {
            const float v = 2.0f * inv * ((float)p0[j] + (float)p1[j]) - (float)afX[mt][j];
            afY2[mt][j] = (__bf16)v;
        }
    }

    const bf16x8* afs[3] = {afX, afY1, afY2};
#pragma unroll
    for (int c = 0; c < 3; ++c) {
#pragma unroll
        for (int ot = 0; ot < 4; ++ot) {
            const bf16x8 bfr = *(const bf16x8*)&Wnode[(size_t)c * 2048 +
                                                      ot * 512 + l16 * 32 + quad * 8];
#pragma unroll
            for (int mt = 0; mt < 2; ++mt)
                acc[mt][ot] = __builtin_amdgcn_mfma_f32_16x16x32_bf16(
                                  afs[c][mt], bfr, acc[mt][ot], 0, 0, 0);
        }
    }

    float en[DEMB];
#pragma unroll
    for (int d = 0; d < DEMB; ++d) en[d] = E[(size_t)n * DEMB + d];
#pragma unroll
    for (int ot = 0; ot < 4; ++ot) {
        float bv = 0.f;
        const int o = ot * 16 + l16;
#pragma unroll
        for (int d = 0; d < DEMB; ++d) bv += en[d] * bias_pool[d * COUT + o];
#pragma unroll
        for (int mt = 0; mt < 2; ++mt)
#pragma unroll
            for (int r = 0; r < 4; ++r) {
                const int b = mt * 16 + quad * 4 + r;
                out[((size_t)b * N_NODES + n) * COUT + o] = acc[mt][ot][r] + bv;
            }
    }
}

// ---------------------------------------------------------------------------
// Workspace map (83.9 MB total, under the proven 117.4 MB):
//   [0,        33554432)  U     (dead after GEMM2)   \
//   [33554432, 41943040)  Bt1   (dead after GEMM1)    } overlaid by Wn (50.3MB)
//   [41943040, 50331648)  Y1t   (dead after GEMM2)   /   after GEMM2
//   [50331648, 67108864)  P     [2][4096][1024] bf16 (GEMM1->combine1, then
//                               GEMM2->final; live through final)
//   [67108864, 75497472)  Y1    (live through final)
//   [75497472, 83886080)  Xt    (live through final)
//   [83886080, 83902464)  invRow (live through final)
// ---------------------------------------------------------------------------
extern "C" void kernel_launch(void* const* d_in, const int* in_sizes, int n_in,
                              void* d_out, int out_size, void* d_ws, size_t ws_size,
                              hipStream_t stream) {
    (void)in_sizes; (void)n_in; (void)out_size; (void)ws_size;
    const float* x  = (const float*)d_in[0];
    const float* E  = (const float*)d_in[1];
    // d_in[2] = laplacian_mx, unused by the reference forward
    const float* Wp = (const float*)d_in[3];
    const float* bp = (const float*)d_in[4];
    float* out = (float*)d_out;

    char* ws = (char*)d_ws;
    __hip_bfloat16* U    = (__hip_bfloat16*)(ws);
    __hip_bfloat16* Bt1  = (__hip_bfloat16*)(ws + 33554432);
    __hip_bfloat16* Y1t  = (__hip_bfloat16*)(ws + 41943040);
    __hip_bfloat16* P    = (__hip_bfloat16*)(ws + 50331648);
    __hip_bfloat16* Y1   = (__hip_bfloat16*)(ws + 67108864);
    __hip_bfloat16* Xt   = (__hip_bfloat16*)(ws + 75497472);
    float*       invRow  = (float*)(ws + 83886080);
    __hip_bfloat16* Wn   = (__hip_bfloat16*)(ws);   // overlays U+Bt1+Y1t post-GEMM2

    compute_U_kernel<<<N_NODES / 8, 256, 0, stream>>>(E, U, invRow);
    transpose_kernel<<<dim3(N_NODES / 64, BATCH), 256, 0, stream>>>(x, Xt, Bt1);
    // Y1 = inv * (U @ X)
    gemm_splitk_kernel<<<dim3(N_NODES / GBM, NCOL / GBN, SPLITK), 512, 0, stream>>>(
        U, Bt1, P, N_NODES, NCOL, N_NODES);
    combine1_kernel<<<dim3(NCOL / 64, N_NODES / 64), 256, 0, stream>>>(
        P, invRow, Y1, Y1t, N_NODES, NCOL);
    // P2 = U @ Y1t partials (combine2 fused into final_kernel)
    gemm_splitk_kernel<<<dim3(N_NODES / GBM, NCOL / GBN, SPLITK), 512, 0, stream>>>(
        U, Y1t, P, N_NODES, NCOL, N_NODES);
    // gen_w AFTER GEMM2: Wn overlays the dead U/Bt1/Y1t region
    gen_w_kernel<<<dim3(24, N_NODES / 64), 256, 0, stream>>>(E, Wp, Wn);
    final_kernel<<<N_NODES / 4, 256, 0, stream>>>(Xt, Y1, P, invRow, Wn, E, bp, out);
}

// Round 5
// 278.956 us; speedup vs baseline: 1.0055x; 1.0017x over previous
//
#include <hip/hip_runtime.h>
#include <hip/hip_bf16.h>

#define N_NODES 4096
#define BATCH   32
#define CIN     32
#define COUT    64
#define DEMB    16
#define NCOL    (BATCH * CIN)      // 1024 columns of the propagation GEMMs
#define KIO     (3 * CIN * COUT)   // 6144 generated-weight elements per node
#define SPLITK  4

typedef __bf16 bf16x8 __attribute__((ext_vector_type(8)));
typedef float  floatx4 __attribute__((ext_vector_type(4)));

__device__ inline void load_lds16(const void* g, void* l) {
    __builtin_amdgcn_global_load_lds(
        (const __attribute__((address_space(1))) void*)g,
        (__attribute__((address_space(3))) void*)l, 16, 0, 0);
}

// ---------------------------------------------------------------------------
// K0: U[n][m] = exp(relu(E[n].E[m])) (UNNORMALIZED, bf16) + invRow[n]=1/rowsum.
// ---------------------------------------------------------------------------
__global__ __launch_bounds__(256) void compute_U_kernel(
        const float* __restrict__ E, __hip_bfloat16* __restrict__ U,
        float* __restrict__ invRow) {
    const int n0   = blockIdx.x * 8;
    const int t    = threadIdx.x;
    const int lane = t & 63, wave = t >> 6;
    __shared__ float red[4][8];

    float en[8][DEMB];
#pragma unroll
    for (int r = 0; r < 8; ++r) {
        const float4* er = (const float4*)&E[(size_t)(n0 + r) * DEMB];
        const float4 a0 = er[0], a1 = er[1], a2 = er[2], a3 = er[3];
        en[r][ 0]=a0.x; en[r][ 1]=a0.y; en[r][ 2]=a0.z; en[r][ 3]=a0.w;
        en[r][ 4]=a1.x; en[r][ 5]=a1.y; en[r][ 6]=a1.z; en[r][ 7]=a1.w;
        en[r][ 8]=a2.x; en[r][ 9]=a2.y; en[r][10]=a2.z; en[r][11]=a2.w;
        en[r][12]=a3.x; en[r][13]=a3.y; en[r][14]=a3.z; en[r][15]=a3.w;
    }

    float sum[8] = {0.f, 0.f, 0.f, 0.f, 0.f, 0.f, 0.f, 0.f};

    for (int tile = 0; tile < 16; ++tile) {
        const int c = tile * 256 + t;
        const float4* em4 = (const float4*)&E[(size_t)c * DEMB];
        const float4 b0 = em4[0], b1 = em4[1], b2 = em4[2], b3 = em4[3];
        float em[DEMB];
        em[ 0]=b0.x; em[ 1]=b0.y; em[ 2]=b0.z; em[ 3]=b0.w;
        em[ 4]=b1.x; em[ 5]=b1.y; em[ 6]=b1.z; em[ 7]=b1.w;
        em[ 8]=b2.x; em[ 9]=b2.y; em[10]=b2.z; em[11]=b2.w;
        em[12]=b3.x; em[13]=b3.y; em[14]=b3.z; em[15]=b3.w;
#pragma unroll
        for (int r = 0; r < 8; ++r) {
            float dt = 0.f;
#pragma unroll
            for (int d = 0; d < DEMB; ++d) dt += en[r][d] * em[d];
            const float ev = __expf(fmaxf(dt, 0.f));
            sum[r] += ev;
            U[(size_t)(n0 + r) * N_NODES + c] = __float2bfloat16(ev);
        }
    }
#pragma unroll
    for (int r = 0; r < 8; ++r)
#pragma unroll
        for (int off = 32; off > 0; off >>= 1) sum[r] += __shfl_xor(sum[r], off);
    if (lane == 0)
#pragma unroll
        for (int r = 0; r < 8; ++r) red[wave][r] = sum[r];
    __syncthreads();
    if (t < 8)
        invRow[n0 + t] = 1.0f / (red[0][t] + red[1][t] + red[2][t] + red[3][t]);
}

// ---------------------------------------------------------------------------
// K1: x[b][m][c] (fp32) -> Xt[m][b*32+c] (bf16) and Bt1[b*32+c][m] (bf16)
// ---------------------------------------------------------------------------
__global__ __launch_bounds__(256) void transpose_kernel(
        const float* __restrict__ x,
        __hip_bfloat16* __restrict__ Xt, __hip_bfloat16* __restrict__ Bt) {
    const int m0 = blockIdx.x * 64;
    const int b  = blockIdx.y;
    const int t  = threadIdx.x;
    __shared__ float tile[64][33];
    {
        const int ml = t >> 2, cg = (t & 3) * 8;
        const float* src = &x[((size_t)b * N_NODES + (m0 + ml)) * CIN + cg];
        const float4 r0 = *(const float4*)src;
        const float4 r1 = *(const float4*)(src + 4);
        tile[ml][cg+0] = r0.x; tile[ml][cg+1] = r0.y; tile[ml][cg+2] = r0.z; tile[ml][cg+3] = r0.w;
        tile[ml][cg+4] = r1.x; tile[ml][cg+5] = r1.y; tile[ml][cg+6] = r1.z; tile[ml][cg+7] = r1.w;
    }
    __syncthreads();
    {
        const int ml = t >> 2, cg = (t & 3) * 8;
        __hip_bfloat16* dst = &Xt[(size_t)(m0 + ml) * NCOL + b * CIN + cg];
#pragma unroll
        for (int j = 0; j < 8; ++j) dst[j] = __float2bfloat16(tile[ml][cg + j]);
    }
    {
        const int c = t >> 3, mg = (t & 7) * 8;
        __hip_bfloat16* dst = &Bt[(size_t)(b * CIN + c) * N_NODES + m0 + mg];
#pragma unroll
        for (int j = 0; j < 8; ++j) dst[j] = __float2bfloat16(tile[mg + j][c]);
    }
}

// ---------------------------------------------------------------------------
// K2 v4: generated weights into the SWIZZLED layout final_kernel reads.
// ---------------------------------------------------------------------------
__global__ __launch_bounds__(256) void gen_w_kernel(
        const float* __restrict__ E, const float* __restrict__ Wp,
        __hip_bfloat16* __restrict__ Wn) {
    const int c   = blockIdx.x >> 3;          // cheb index 0..2
    const int oo0 = (blockIdx.x & 7) * 8;     // output-col group base
    const int nc  = blockIdx.y * 64;          // node group
    const int t   = threadIdx.x;
    const int kk  = t & 31;                   // within-c row index 0..31
    const int oo  = oo0 + (t >> 5);           // output col 0..63

    __shared__ float et[64][DEMB];            // 4 KB: 64 E rows
    ((float4*)et)[t] = ((const float4*)&E[(size_t)nc * DEMB])[t];
    __syncthreads();

    const int srccol = (c * 32 + kk) * 64 + oo;
    float w[DEMB];
#pragma unroll
    for (int d = 0; d < DEMB; ++d) w[d] = Wp[(size_t)d * KIO + srccol];

    const int dstoff = c * 2048 + (oo >> 4) * 512 + (oo & 15) * 32 + kk;
    for (int nl = 0; nl < 64; ++nl) {
        float acc = 0.0f;
#pragma unroll
        for (int d = 0; d < DEMB; ++d) acc += et[nl][d] * w[d];
        Wn[(size_t)(nc + nl) * KIO + dstoff] = __float2bfloat16(acc);
    }
}

// ---------------------------------------------------------------------------
// K3 (round-3 gemm_pipe, the measured ~38 us winner): de-pinned deep pipeline.
//   BM=BN=256, BK=64, 512 thr = 8 waves (2Mx4N), wave tile 128x64.
//   2 LDS buffers (128 KB, 1 block/CU); per tile 2 K-half chunks of 16 KB;
//   row-pair XOR granule swizzle (verified bijection), lane-linear
//   global_load_lds dest + inverse-swizzled global source + swizzled ds_read.
//   4 phases/K-tile: {ds_read frags -> 2 stage calls -> barrier ->
//   setprio(1)+16 MFMA+setprio(0) -> barrier}.  Counted vmcnt(4) once per
//   K-tile; vmcnt(0) only at NT-2.  NO sched_barrier / lgkmcnt pins
//   (round-3 A/B: pins cost ~10%).  SPLITK=4 -> grid 16x4x4 = 256 blocks.
// ---------------------------------------------------------------------------
#define GBM 256
#define GBN 256
#define GBK 64

__global__ __launch_bounds__(512, 2) void gemm_splitk_kernel(
        const __hip_bfloat16* __restrict__ A,    // [M][K]
        const __hip_bfloat16* __restrict__ Bt,   // [NC][K]
        __hip_bfloat16* __restrict__ P,          // [SPLITK][M][NC] bf16 partials
        int M, int NC, int K) {
    const int t    = threadIdx.x;
    const int row0 = blockIdx.x * GBM;
    const int col0 = blockIdx.y * GBN;
    const int z    = blockIdx.z;
    const int NT   = (K >> 6) / SPLITK;        // 16 K-tiles of BK=64 per block
    const int kb0  = z * NT * GBK;

    __shared__ alignas(16) __hip_bfloat16 As[2][16384];  // 2 x 32 KB
    __shared__ alignas(16) __hip_bfloat16 Bs[2][16384];  // 2 x 32 KB

    const int lane = t & 63, wave = t >> 6;
    const int l16 = lane & 15, quad = lane >> 4;
    const int wr = wave >> 2, wc = wave & 3;   // 2 x 4 wave grid

    const int R0 = wr * 128 + l16;             // A row base
    const int C0 = wc * 64 + l16;              // B row base
    const int u_par = (l16 & 1) * 4 + quad;
    const int Aoff = (R0 >> 1) * 64 + ((u_par ^ ((R0 >> 1) & 7)) * 8);
    const int Boff = (C0 >> 1) * 64 + ((u_par ^ ((C0 >> 1) & 7)) * 8);

    auto stageA = [&](int buf, int kb, int kh, int s) {
        const int L = s * 512 + t;
        const int p = L >> 3, j = L & 7;
        const int u = j ^ (p & 7);
        const int rr = p * 2 + (u >> 2);
        const int qq = u & 3;
        load_lds16(&A[(size_t)(row0 + rr) * K + kb + kh * 32 + qq * 8],
                   &As[buf][(size_t)(kh * 1024 + L) * 8]);
    };
    auto stageB = [&](int buf, int kb, int kh, int s) {
        const int L = s * 512 + t;
        const int p = L >> 3, j = L & 7;
        const int u = j ^ (p & 7);
        const int rr = p * 2 + (u >> 2);
        const int qq = u & 3;
        load_lds16(&Bt[(size_t)(col0 + rr) * K + kb + kh * 32 + qq * 8],
                   &Bs[buf][(size_t)(kh * 1024 + L) * 8]);
    };

    floatx4 acc[8][4] = {};

    // prologue: tile0 fully + tile1 kh0; wait tile0 (4 of t1 in flight)
#pragma unroll
    for (int s = 0; s < 2; ++s) stageA(0, kb0, 0, s);
#pragma unroll
    for (int s = 0; s < 2; ++s) stageB(0, kb0, 0, s);
#pragma unroll
    for (int s = 0; s < 2; ++s) stageA(0, kb0, 1, s);
#pragma unroll
    for (int s = 0; s < 2; ++s) stageB(0, kb0, 1, s);
#pragma unroll
    for (int s = 0; s < 2; ++s) stageA(1, kb0 + GBK, 0, s);
#pragma unroll
    for (int s = 0; s < 2; ++s) stageB(1, kb0 + GBK, 0, s);
    asm volatile("s_waitcnt vmcnt(4)" ::: "memory");
    __builtin_amdgcn_s_barrier();

    for (int tt = 0; tt < NT; ++tt) {
        const int buf = tt & 1;
        const int nb1 = buf ^ 1;
        const int nb2 = buf;
        const int kb1 = kb0 + (tt + 1) * GBK;
        const int kb2 = kb0 + (tt + 2) * GBK;
        const bool g1 = (tt + 1 < NT), g2 = (tt + 2 < NT);

        bf16x8 bfrag[4], afrag[4];

        // ===== phase 1: kq=0, mq=0 =====
#pragma unroll
        for (int n = 0; n < 4; ++n)
            bfrag[n] = *(const bf16x8*)&Bs[buf][n * 512 + Boff];
#pragma unroll
        for (int m = 0; m < 4; ++m)
            afrag[m] = *(const bf16x8*)&As[buf][m * 512 + Aoff];
        if (g1) { stageA(nb1, kb1, 1, 0); stageA(nb1, kb1, 1, 1); }
        __builtin_amdgcn_s_barrier();
        __builtin_amdgcn_s_setprio(1);
#pragma unroll
        for (int m = 0; m < 4; ++m)
#pragma unroll
            for (int n = 0; n < 4; ++n)
                acc[m][n] = __builtin_amdgcn_mfma_f32_16x16x32_bf16(
                                afrag[m], bfrag[n], acc[m][n], 0, 0, 0);
        __builtin_amdgcn_s_setprio(0);
        __builtin_amdgcn_s_barrier();

        // ===== phase 2: kq=0, mq=1 =====
#pragma unroll
        for (int m = 0; m < 4; ++m)
            afrag[m] = *(const bf16x8*)&As[buf][2048 + m * 512 + Aoff];
        if (g1) { stageB(nb1, kb1, 1, 0); stageB(nb1, kb1, 1, 1); }
        __builtin_amdgcn_s_barrier();
        __builtin_amdgcn_s_setprio(1);
#pragma unroll
        for (int m = 0; m < 4; ++m)
#pragma unroll
            for (int n = 0; n < 4; ++n)
                acc[4 + m][n] = __builtin_amdgcn_mfma_f32_16x16x32_bf16(
                                    afrag[m], bfrag[n], acc[4 + m][n], 0, 0, 0);
        __builtin_amdgcn_s_setprio(0);
        __builtin_amdgcn_s_barrier();

        // ===== phase 3: kq=1, mq=0 =====
#pragma unroll
        for (int n = 0; n < 4; ++n)
            bfrag[n] = *(const bf16x8*)&Bs[buf][8192 + n * 512 + Boff];
#pragma unroll
        for (int m = 0; m < 4; ++m)
            afrag[m] = *(const bf16x8*)&As[buf][8192 + m * 512 + Aoff];
        if (g2) { stageA(nb2, kb2, 0, 0); stageA(nb2, kb2, 0, 1); }
        __builtin_amdgcn_s_barrier();
        __builtin_amdgcn_s_setprio(1);
#pragma unroll
        for (int m = 0; m < 4; ++m)
#pragma unroll
            for (int n = 0; n < 4; ++n)
                acc[m][n] = __builtin_amdgcn_mfma_f32_16x16x32_bf16(
                                afrag[m], bfrag[n], acc[m][n], 0, 0, 0);
        __builtin_amdgcn_s_setprio(0);
        __builtin_amdgcn_s_barrier();

        // ===== phase 4: kq=1, mq=1 =====
#pragma unroll
        for (int m = 0; m < 4; ++m)
            afrag[m] = *(const bf16x8*)&As[buf][8192 + 2048 + m * 512 + Aoff];
        if (g2) { stageB(nb2, kb2, 0, 0); stageB(nb2, kb2, 0, 1); }
        __builtin_amdgcn_s_barrier();
        __builtin_amdgcn_s_setprio(1);
#pragma unroll
        for (int m = 0; m < 4; ++m)
#pragma unroll
            for (int n = 0; n < 4; ++n)
                acc[4 + m][n] = __builtin_amdgcn_mfma_f32_16x16x32_bf16(
                                    afrag[m], bfrag[n], acc[4 + m][n], 0, 0, 0);
        __builtin_amdgcn_s_setprio(0);
        if (tt < NT - 2) asm volatile("s_waitcnt vmcnt(4)" ::: "memory");
        else             asm volatile("s_waitcnt vmcnt(0)" ::: "memory");
        __builtin_amdgcn_s_barrier();
    }

    __hip_bfloat16* Pz = P + (size_t)z * M * NC;
#pragma unroll
    for (int mq = 0; mq < 2; ++mq)
#pragma unroll
        for (int m = 0; m < 4; ++m)
#pragma unroll
            for (int n = 0; n < 4; ++n)
#pragma unroll
                for (int r = 0; r < 4; ++r) {
                    const int rg = row0 + wr * 128 + mq * 64 + m * 16 + quad * 4 + r;
                    const int cg = col0 + wc * 64 + n * 16 + l16;
                    Pz[(size_t)rg * NC + cg] = __float2bfloat16(acc[mq * 4 + m][n][r]);
                }
}

// ---------------------------------------------------------------------------
// K3b: combine1 -> Y1 = bf16(inv[row] * sum_z Pz), plus transposed Y1t
// ---------------------------------------------------------------------------
__global__ __launch_bounds__(256) void combine1_kernel(
        const __hip_bfloat16* __restrict__ P, const float* __restrict__ invRow,
        __hip_bfloat16* __restrict__ Y, __hip_bfloat16* __restrict__ Yt,
        int M, int NC) {
    const int c0 = blockIdx.x * 64, m0 = blockIdx.y * 64;
    const int t = threadIdx.x;
    __shared__ float tile[64][65];
    const size_t stride = (size_t)M * NC;
#pragma unroll
    for (int j = 0; j < 16; ++j) {
        const int lin = t + j * 256;
        const int r = lin >> 6, c = lin & 63;
        const size_t idx = (size_t)(m0 + r) * NC + c0 + c;
        float s = 0.f;
#pragma unroll
        for (int z = 0; z < SPLITK; ++z) s += __bfloat162float(P[idx + z * stride]);
        s *= invRow[m0 + r];
        tile[r][c] = s;
        Y[idx] = __float2bfloat16(s);
    }
    __syncthreads();
#pragma unroll
    for (int j = 0; j < 16; ++j) {
        const int lin = t + j * 256;
        const int c = lin >> 6, r = lin & 63;
        Yt[(size_t)(c0 + c) * M + m0 + r] = __float2bfloat16(tile[r][c]);
    }
}

// ---------------------------------------------------------------------------
// K4 v3: per-node grouped GEMM via MFMA, combine2 FUSED (Y2 from 4 partials),
// plus LDS-transposed store epilogue: out written as float4 in 1KB-contiguous
// runs per wave (was 32 scalar dword stores in 64B segments per thread).
// ---------------------------------------------------------------------------
__global__ __launch_bounds__(256) void final_kernel(
        const __hip_bfloat16* __restrict__ Xt, const __hip_bfloat16* __restrict__ Y1,
        const __hip_bfloat16* __restrict__ P,  const float* __restrict__ invRow,
        const __hip_bfloat16* __restrict__ Wn,
        const float* __restrict__ E, const float* __restrict__ bias_pool,
        float* __restrict__ out) {
    const int t    = threadIdx.x;
    const int lane = t & 63, wave = t >> 6;
    const int l16  = lane & 15, quad = lane >> 4;
    const int n0   = blockIdx.x * 4;
    const int n    = n0 + wave;

    __shared__ float ost[32][4][65];   // [b][node-in-block][o], pad->2-way max

    const __hip_bfloat16* Wnode = Wn + (size_t)n * KIO;   // [c][ot][l16][kk]
    const float inv = invRow[n];
    const size_t pstride = (size_t)N_NODES * NCOL;

    floatx4 acc[2][4] = {};   // [mt][ot]

    bf16x8 afX[2], afY1[2], afY2[2];
#pragma unroll
    for (int mt = 0; mt < 2; ++mt) {
        const size_t fo = (size_t)n * NCOL + (mt * 16 + l16) * 32 + quad * 8;
        afX[mt]  = *(const bf16x8*)&Xt[fo];
        afY1[mt] = *(const bf16x8*)&Y1[fo];
        const bf16x8 p0 = *(const bf16x8*)&P[fo];
        const bf16x8 p1 = *(const bf16x8*)&P[fo + pstride];
        const bf16x8 p2 = *(const bf16x8*)&P[fo + 2 * pstride];
        const bf16x8 p3 = *(const bf16x8*)&P[fo + 3 * pstride];
#pragma unroll
        for (int j = 0; j < 8; ++j) {
            const float s = (float)p0[j] + (float)p1[j] + (float)p2[j] + (float)p3[j];
            afY2[mt][j] = (__bf16)(2.0f * inv * s - (float)afX[mt][j]);
        }
    }

    const bf16x8* afs[3] = {afX, afY1, afY2};
#pragma unroll
    for (int c = 0; c < 3; ++c) {
#pragma unroll
        for (int ot = 0; ot < 4; ++ot) {
            const bf16x8 bfr = *(const bf16x8*)&Wnode[(size_t)c * 2048 +
                                                      ot * 512 + l16 * 32 + quad * 8];
#pragma unroll
            for (int mt = 0; mt < 2; ++mt)
                acc[mt][ot] = __builtin_amdgcn_mfma_f32_16x16x32_bf16(
                                  afs[c][mt], bfr, acc[mt][ot], 0, 0, 0);
        }
    }

    float en[DEMB];
#pragma unroll
    for (int d = 0; d < DEMB; ++d) en[d] = E[(size_t)n * DEMB + d];
#pragma unroll
    for (int ot = 0; ot < 4; ++ot) {
        float bv = 0.f;
        const int o = ot * 16 + l16;
#pragma unroll
        for (int d = 0; d < DEMB; ++d) bv += en[d] * bias_pool[d * COUT + o];
#pragma unroll
        for (int mt = 0; mt < 2; ++mt)
#pragma unroll
            for (int r = 0; r < 4; ++r) {
                const int b = mt * 16 + quad * 4 + r;
                ost[b][wave][o] = acc[mt][ot][r] + bv;
            }
    }
    __syncthreads();

    // coalesced writeback: chunk c covers (b, nl, o4); per wave 1KB contiguous
#pragma unroll
    for (int j = 0; j < 8; ++j) {
        const int c  = t + j * 256;        // float4 chunk id 0..2047
        const int b  = c >> 6;
        const int rm = c & 63;
        const int nl = rm >> 4, o4 = (rm & 15) * 4;
        float4 v;
        v.x = ost[b][nl][o4 + 0]; v.y = ost[b][nl][o4 + 1];
        v.z = ost[b][nl][o4 + 2]; v.w = ost[b][nl][o4 + 3];
        *(float4*)&out[((size_t)b * N_NODES + n0 + nl) * COUT + o4] = v;
    }
}

// ---------------------------------------------------------------------------
// Workspace map (100.7 MB, under the proven 117.4 MB):
//   [0,         33554432)  U    (dead after GEMM2)  \
//   [33554432,  41943040)  Bt1  (dead after GEMM1)   } overlaid by Wn (50.3MB)
//   [41943040,  50331648)  Y1t  (dead after GEMM2)  /   after GEMM2
//   [50331648,  83886080)  P    [4][4096][1024] bf16 (live through final)
//   [83886080,  92274688)  Y1   (live through final)
//   [92274688, 100663296)  Xt   (live through final)
//   [100663296,100679680)  invRow (live through final)
// ---------------------------------------------------------------------------
extern "C" void kernel_launch(void* const* d_in, const int* in_sizes, int n_in,
                              void* d_out, int out_size, void* d_ws, size_t ws_size,
                              hipStream_t stream) {
    (void)in_sizes; (void)n_in; (void)out_size; (void)ws_size;
    const float* x  = (const float*)d_in[0];
    const float* E  = (const float*)d_in[1];
    // d_in[2] = laplacian_mx, unused by the reference forward
    const float* Wp = (const float*)d_in[3];
    const float* bp = (const float*)d_in[4];
    float* out = (float*)d_out;

    char* ws = (char*)d_ws;
    __hip_bfloat16* U    = (__hip_bfloat16*)(ws);
    __hip_bfloat16* Bt1  = (__hip_bfloat16*)(ws + 33554432);
    __hip_bfloat16* Y1t  = (__hip_bfloat16*)(ws + 41943040);
    __hip_bfloat16* P    = (__hip_bfloat16*)(ws + 50331648);
    __hip_bfloat16* Y1   = (__hip_bfloat16*)(ws + 83886080);
    __hip_bfloat16* Xt   = (__hip_bfloat16*)(ws + 92274688);
    float*       invRow  = (float*)(ws + 100663296);
    __hip_bfloat16* Wn   = (__hip_bfloat16*)(ws);   // overlays U+Bt1+Y1t post-GEMM2

    compute_U_kernel<<<N_NODES / 8, 256, 0, stream>>>(E, U, invRow);
    transpose_kernel<<<dim3(N_NODES / 64, BATCH), 256, 0, stream>>>(x, Xt, Bt1);
    // Y1 = inv * (U @ X)
    gemm_splitk_kernel<<<dim3(N_NODES / GBM, NCOL / GBN, SPLITK), 512, 0, stream>>>(
        U, Bt1, P, N_NODES, NCOL, N_NODES);
    combine1_kernel<<<dim3(NCOL / 64, N_NODES / 64), 256, 0, stream>>>(
        P, invRow, Y1, Y1t, N_NODES, NCOL);
    // P = U @ Y1t partials (combine2 fused into final_kernel)
    gemm_splitk_kernel<<<dim3(N_NODES / GBM, NCOL / GBN, SPLITK), 512, 0, stream>>>(
        U, Y1t, P, N_NODES, NCOL, N_NODES);
    // gen_w AFTER GEMM2: Wn overlays the dead U/Bt1/Y1t region
    gen_w_kernel<<<dim3(24, N_NODES / 64), 256, 0, stream>>>(E, Wp, Wn);
    final_kernel<<<N_NODES / 4, 256, 0, stream>>>(Xt, Y1, P, invRow, Wn, E, bp, out);
}